// Round 14
// baseline (967.263 us; speedup 1.0000x reference)
//
#include <hip/hip_runtime.h>

#define M_DIM 8192
#define N_DIM 11008
#define K_DIM 4096
#define GROUPS 32     // K / 128
#define WQROW 512     // dwords per row of compact W = K/8
#define LDSK 72       // slow kernel pad

typedef short s16x8 __attribute__((ext_vector_type(8)));
typedef _Float16 f16x8 __attribute__((ext_vector_type(8)));
typedef _Float16 h2 __attribute__((ext_vector_type(2)));
typedef float f32x4 __attribute__((ext_vector_type(4)));
typedef unsigned short u16;
typedef unsigned int u32;

union f32u { float f; unsigned u; };
union h16u { u16 u; _Float16 h; };

__device__ __forceinline__ u16 f2bf(float f) {
  f32u v; v.f = f;
  unsigned r = v.u + 0x7FFFu + ((v.u >> 16) & 1u);  // RNE
  return (u16)(r >> 16);
}
__device__ __forceinline__ float bf2f(u16 b) {
  f32u v; v.u = ((unsigned)b) << 16; return v.f;
}
__device__ __forceinline__ float h2f(u16 b) {
  h16u v; v.u = b; return (float)v.h;
}

// ---------------------------------------------------------------------------
// Probe (R3/R4 empirics: harness promotes fp16 -> f32 => mode 0).
// ---------------------------------------------------------------------------
__global__ void probe_mode_kernel(const void* __restrict__ scales,
                                  int* __restrict__ mode_out) {
  __shared__ int cnt[3];
  int t = threadIdx.x;
  if (t < 3) cnt[t] = 0;
  __syncthreads();
  float f0 = ((const float*)scales)[t];
  u16  hu  = ((const u16*)scales)[t];
  float f1 = h2f(hu);
  float f2 = bf2f(hu);
  if (f0 > 0.0004f && f0 < 0.065f) atomicAdd(&cnt[0], 1);
  if (f1 > 0.0004f && f1 < 0.065f) atomicAdd(&cnt[1], 1);
  if (f2 > 0.0004f && f2 < 0.065f) atomicAdd(&cnt[2], 1);
  __syncthreads();
  if (t == 0) {
    int m;
    if      (cnt[1] >= 240) m = 1;
    else if (cnt[2] >= 240) m = 2;
    else                    m = 0;
    mode_out[0] = m;
  }
}

// ---------------------------------------------------------------------------
// BIG-PATH pre-pass 1: x f32 -> fp16, NATURAL order (exact).
// ---------------------------------------------------------------------------
__global__ __launch_bounds__(256) void convert_x_nat_kernel(
    const float* __restrict__ xf, u16* __restrict__ xh,
    const int* __restrict__ modep) {
  if (modep && modep[0] != 0) return;
  const int total8 = M_DIM * (K_DIM / 8);
  int idx = blockIdx.x * 256 + threadIdx.x;
  const int stride = gridDim.x * 256;
  for (; idx < total8; idx += stride) {
    const float4* p = (const float4*)(xf + (size_t)idx * 8);
    float4 a = p[0], b = p[1];
    union { _Float16 h[8]; s16x8 v; } r;
    r.h[0] = (_Float16)a.x; r.h[1] = (_Float16)a.y;
    r.h[2] = (_Float16)a.z; r.h[3] = (_Float16)a.w;
    r.h[4] = (_Float16)b.x; r.h[5] = (_Float16)b.y;
    r.h[6] = (_Float16)b.z; r.h[7] = (_Float16)b.w;
    *(s16x8*)(xh + (size_t)idx * 8) = r.v;
  }
}

// ---------------------------------------------------------------------------
// BIG-PATH pre-pass 2: full dequant W -> fp16 [N][K], natural order.
// ---------------------------------------------------------------------------
__global__ __launch_bounds__(256) void dequant_w_kernel(
    const int* __restrict__ packed, const float* __restrict__ scf,
    u16* __restrict__ wf, const int* __restrict__ modep) {
  if (modep && modep[0] != 0) return;
  const int total = N_DIM * (K_DIM / 8);    // 5,636,096 chunks
  int idx = blockIdx.x * 256 + threadIdx.x;
  const int stride = gridDim.x * 256;
  for (; idx < total; idx += stride) {
    const int col = idx >> 9;               // K/8 = 512 chunks per row
    const int d   = idx & 511;
    const float s = scf[col * GROUPS + (d >> 4)];
    const int4 p  = ((const int4*)packed)[idx];
    const int vals[4] = {p.x, p.y, p.z, p.w};
    union { _Float16 h[8]; s16x8 v; } r;
    #pragma unroll
    for (int e = 0; e < 4; ++e) {
      int b = vals[e] & 255;
      r.h[2 * e]     = (_Float16)((float)((b & 15) - 8) * s);
      r.h[2 * e + 1] = (_Float16)((float)(((b >> 4) & 15) - 8) * s);
    }
    *(s16x8*)(wf + (size_t)idx * 8) = r.v;
  }
}

// ---------------------------------------------------------------------------
// BIG-PATH GEMM (R14): 256x256 block, 8 waves (2m x 4n), BK=64 — m201-style
// template. BOTH A and B staged in LDS via global_load_lds (R13 was bound by
// exposed B-from-global latency; prefetch depth now lives in LDS, not VGPRs).
//  - LDS 128 KiB: A[2][256x64] + B[2][256x64] fp16, double-buffered.
//  - Tile t: entry vmcnt(0)+barrier (stages of t, issued at t-1 entry, are
//    the ONLY outstanding vmem -> wait is exact); then issue all 8 stage
//    gloads for t+1 (max slack ~4 sub-phases); then 4 sub-phases
//    (kkc x ihalf): ds_read frags -> barrier -> lgkmcnt(0)+sched_barrier ->
//    setprio(1) + 16 MFMA + setprio(0) -> barrier.
//  - Race ledger: stages write buf cur^1 only; reads hit buf cur; entry
//    barrier separates buffer generations; barriers uniform across waves.
//  - XOR swizzle on A and B reads (0 LDS conflicts, proven R4-R13).
// ---------------------------------------------------------------------------
__global__ __launch_bounds__(512, 2) void q4gemm_big_kernel(
    const u16* __restrict__ xh,      // fp16 natural [M][K]
    const u16* __restrict__ wf,      // fp16 W [N][K]
    float* __restrict__ out,
    const int* __restrict__ modep)
{
  if (modep && modep[0] != 0) return;

  __shared__ _Float16 AsA[2][256 * 64];   // 64 KiB
  __shared__ _Float16 AsB[2][256 * 64];   // 64 KiB

  const int tid  = threadIdx.x;
  const int lane = tid & 63;
  const int wv   = tid >> 6;             // 0..7
  const int wm   = (wv >> 2) * 128;      // 2 waves in m
  const int wn   = (wv & 3) * 64;        // 4 waves in n
  const int ln15 = lane & 15;
  const int lk   = lane >> 4;            // 0..3

  // XCD swizzle: 1376 = 8 * 172; per-XCD contiguous f, bn = f/32 (bm-fastest
  // within a bn group -> same-XCD neighbors share the 2MB B panel).
  int bid = blockIdx.x;
  int f   = (bid & 7) * 172 + (bid >> 3);
  int bn  = f / 32;                      // 0..42
  int bm  = f - bn * 32;                 // 0..31
  const int m0 = bm * 256;
  const int n0 = bn * 256;

  // Staging addresses: LDS[row][slot] = G[row][slot ^ (row&7)] (16B chunks).
  // Per q (64-row group) each wave stages 8 rows x 64k linearly.
  const int srow  = lane >> 3;           // 0..7
  const int sperm = (lane & 7) ^ srow;
  const u16* abase[4];
  const u16* bbase[4];
  #pragma unroll
  for (int q = 0; q < 4; ++q) {
    int row = q * 64 + wv * 8 + srow;
    abase[q] = xh + (size_t)(m0 + row) * K_DIM + sperm * 8;
    bbase[q] = wf + (size_t)(n0 + row) * K_DIM + sperm * 8;
  }

#define STAGE_ALL(PB, T) do { \
    _Float16* da = &AsA[(PB)][0]; \
    _Float16* db = &AsB[(PB)][0]; \
    _Pragma("unroll") \
    for (int q = 0; q < 4; ++q) \
      __builtin_amdgcn_global_load_lds( \
          (const __attribute__((address_space(1))) void*)(abase[q] + (T) * 64), \
          (__attribute__((address_space(3))) void*)(da + q * 4096 + wv * 512), \
          16, 0, 0); \
    _Pragma("unroll") \
    for (int q = 0; q < 4; ++q) \
      __builtin_amdgcn_global_load_lds( \
          (const __attribute__((address_space(1))) void*)(bbase[q] + (T) * 64), \
          (__attribute__((address_space(3))) void*)(db + q * 4096 + wv * 512), \
          16, 0, 0); \
  } while (0)

  f32x4 acc[8][4];
  #pragma unroll
  for (int i = 0; i < 8; ++i)
    #pragma unroll
    for (int j = 0; j < 4; ++j)
      acc[i][j] = f32x4{0.f, 0.f, 0.f, 0.f};

  // prologue: stage tile 0 into buf 0 (loop entry waits on it)
  STAGE_ALL(0, 0);

  #pragma unroll 1
  for (int t = 0; t < 64; ++t) {
    const int cur = t & 1;

    // tile entry: stages of tile t landed (only outstanding vmem)
    asm volatile("s_waitcnt vmcnt(0)" ::: "memory");
    __builtin_amdgcn_s_barrier();

    // earliest-issue prefetch of tile t+1 (max latency slack)
    if (t < 63) STAGE_ALL(cur ^ 1, t + 1);

    const _Float16* Ab = &AsA[cur][0];
    const _Float16* Bb = &AsB[cur][0];
    const int slotx = ln15 & 7;

    #pragma unroll
    for (int kkc = 0; kkc < 2; ++kkc) {
      const int slot = (kkc * 4 + lk) ^ slotx;
      f16x8 bf[4];
      #pragma unroll
      for (int j = 0; j < 4; ++j) {
        int r = wn + j * 16 + ln15;
        bf[j] = *(const f16x8*)&Bb[r * 64 + slot * 8];
      }
      #pragma unroll
      for (int ih = 0; ih < 2; ++ih) {
        f16x8 af[4];
        #pragma unroll
        for (int ii = 0; ii < 4; ++ii) {
          int r = wm + (ih * 4 + ii) * 16 + ln15;
          af[ii] = *(const f16x8*)&Ab[r * 64 + slot * 8];
        }
        __builtin_amdgcn_s_barrier();
        asm volatile("s_waitcnt lgkmcnt(0)" ::: "memory");
        __builtin_amdgcn_sched_barrier(0);
        __builtin_amdgcn_s_setprio(1);
        #pragma unroll
        for (int ii = 0; ii < 4; ++ii) {
          acc[ih * 4 + ii][0] = __builtin_amdgcn_mfma_f32_16x16x32_f16(af[ii], bf[0], acc[ih * 4 + ii][0], 0, 0, 0);
          acc[ih * 4 + ii][1] = __builtin_amdgcn_mfma_f32_16x16x32_f16(af[ii], bf[1], acc[ih * 4 + ii][1], 0, 0, 0);
          acc[ih * 4 + ii][2] = __builtin_amdgcn_mfma_f32_16x16x32_f16(af[ii], bf[2], acc[ih * 4 + ii][2], 0, 0, 0);
          acc[ih * 4 + ii][3] = __builtin_amdgcn_mfma_f32_16x16x32_f16(af[ii], bf[3], acc[ih * 4 + ii][3], 0, 0, 0);
        }
        __builtin_amdgcn_s_setprio(0);
        __builtin_amdgcn_s_barrier();
      }
    }
  }

  // epilogue: C/D col=lane&15, row=(lane>>4)*4+reg — nontemporal stores.
  #pragma unroll
  for (int i = 0; i < 8; ++i) {
    int r0 = m0 + wm + i * 16 + (lane >> 4) * 4;
    #pragma unroll
    for (int j = 0; j < 4; ++j) {
      int cc = n0 + wn + j * 16 + ln15;
      #pragma unroll
      for (int r = 0; r < 4; ++r)
        __builtin_nontemporal_store(acc[i][j][r], &out[(size_t)(r0 + r) * N_DIM + cc]);
    }
  }
#undef STAGE_ALL
}

// ---------------------------------------------------------------------------
// MID PATH (R10 verified; runs only if ws fits 90MB but not 157MB).
// ---------------------------------------------------------------------------
__global__ __launch_bounds__(256) void convert_x_perm_kernel(
    const float* __restrict__ xf, u16* __restrict__ xh,
    const int* __restrict__ modep) {
  if (modep && modep[0] != 0) return;
  const int total8 = M_DIM * (K_DIM / 8);
  int idx = blockIdx.x * 256 + threadIdx.x;
  const int stride = gridDim.x * 256;
  for (; idx < total8; idx += stride) {
    const float4* p = (const float4*)(xf + (size_t)idx * 8);
    float4 a = p[0], b = p[1];
    union { _Float16 h[8]; s16x8 v; } r;
    r.h[0] = (_Float16)a.x; r.h[1] = (_Float16)b.x;
    r.h[2] = (_Float16)a.y; r.h[3] = (_Float16)b.y;
    r.h[4] = (_Float16)a.z; r.h[5] = (_Float16)b.z;
    r.h[6] = (_Float16)a.w; r.h[7] = (_Float16)b.w;
    *(s16x8*)(xh + (size_t)idx * 8) = r.v;
  }
}

__global__ __launch_bounds__(256) void repack_w_kernel(
    const int* __restrict__ packed, u32* __restrict__ wq) {
  const int total = N_DIM * WQROW;
  int idx = blockIdx.x * 256 + threadIdx.x;
  const int stride = gridDim.x * 256;
  for (; idx < total; idx += stride) {
    const int4 p = ((const int4*)packed)[idx];
    wq[idx] = (u32)(p.x & 255) | ((u32)(p.y & 255) << 8) |
              ((u32)(p.z & 255) << 16) | ((u32)p.w << 24);
  }
}

__device__ __forceinline__ f16x8 dq8(u32 q, h2 s2) {
  const u32 M = 0x000F000Fu, G = 0x64006400u;
  const h2 bias = {(_Float16)(-1032.0f), (_Float16)(-1032.0f)};
  union { u32 u; h2 h; } a0, a1, a2, a3;
  a0.u = (q & M) | G;
  a1.u = ((q >> 4) & M) | G;
  a2.u = ((q >> 8) & M) | G;
  a3.u = ((q >> 12) & M) | G;
  a0.h = (a0.h + bias) * s2;
  a1.h = (a1.h + bias) * s2;
  a2.h = (a2.h + bias) * s2;
  a3.h = (a3.h + bias) * s2;
  union { u32 u[4]; f16x8 f; } r;
  r.u[0] = a0.u; r.u[1] = a1.u; r.u[2] = a2.u; r.u[3] = a3.u;
  return r.f;
}

__global__ __launch_bounds__(256, 2) void q4gemm_mid_kernel(
    const u16* __restrict__ xh, const u32* __restrict__ wq,
    const float* __restrict__ scf, float* __restrict__ out,
    const int* __restrict__ modep)
{
  if (modep && modep[0] != 0) return;

  __shared__ _Float16 As[3][128 * 64];

  const int tid  = threadIdx.x;
  const int lane = tid & 63;
  const int wv   = tid >> 6;
  const int wn   = wv * 64;
  const int ln15 = lane & 15;
  const int lk   = lane >> 4;

  int bid = blockIdx.x;
  int f   = (bid & 7) * 344 + (bid >> 3);
  int bn  = f / 64;
  int bm  = f - bn * 64;
  const int m0 = bm * 128;
  const int n0 = bn * 256;

  const u16* abase[4];
  #pragma unroll
  for (int q = 0; q < 4; ++q) {
    int row = q * 32 + wv * 8 + (lane >> 3);
    abase[q] = xh + (size_t)(m0 + row) * K_DIM + (((lane & 7) ^ (lane >> 3)) * 8);
  }

#define STAGE(PB, T) do { \
    _Float16* dst = &As[(PB)][0]; \
    _Pragma("unroll") \
    for (int q = 0; q < 4; ++q) \
      __builtin_amdgcn_global_load_lds( \
          (const __attribute__((address_space(1))) void*)(abase[q] + (T) * 64), \
          (__attribute__((address_space(3))) void*)(dst + q * 2048 + wv * 512), \
          16, 0, 0); \
  } while (0)

#define LOADB(RB, T) do { \
    _Pragma("unroll") \
    for (int j = 0; j < 4; ++j) { \
      RB[j]     = wq[pcol[j] + (T) * 8]; \
      RB[j + 4] = wq[pcol[j] + (T) * 8 + 4]; \
    } \
  } while (0)

#define COMPUTE(RB, PB) do { \
    const _Float16* asb = &As[(PB)][0]; \
    _Pragma("unroll") \
    for (int kkc = 0; kkc < 2; ++kkc) { \
      f16x8 bfr0 = dq8(RB[kkc * 4 + 0], s2[0]); \
      f16x8 bfr1 = dq8(RB[kkc * 4 + 1], s2[1]); \
      f16x8 bfr2 = dq8(RB[kkc * 4 + 2], s2[2]); \
      f16x8 bfr3 = dq8(RB[kkc * 4 + 3], s2[3]); \
      _Pragma("unroll") \
      for (int i = 0; i < 8; ++i) { \
        const int row  = i * 16 + ln15; \
        const int slot = (kkc * 4 + lk) ^ (ln15 & 7); \
        f16x8 af = *(const f16x8*)&asb[row * 64 + slot * 8]; \
        acc[i][0] = __builtin_amdgcn_mfma_f32_16x16x32_f16(af, bfr0, acc[i][0], 0, 0, 0); \
        acc[i][1] = __builtin_amdgcn_mfma_f32_16x16x32_f16(af, bfr1, acc[i][1], 0, 0, 0); \
        acc[i][2] = __builtin_amdgcn_mfma_f32_16x16x32_f16(af, bfr2, acc[i][2], 0, 0, 0); \
        acc[i][3] = __builtin_amdgcn_mfma_f32_16x16x32_f16(af, bfr3, acc[i][3], 0, 0, 0); \
      } \
    } \
  } while (0)

  int pcol[4], scol[4];
  #pragma unroll
  for (int j = 0; j < 4; ++j) {
    int col = n0 + wn + j * 16 + ln15;
    pcol[j] = col * WQROW + lk;
    scol[j] = col * GROUPS;
  }

  f32x4 acc[8][4];
  #pragma unroll
  for (int i = 0; i < 8; ++i)
    #pragma unroll
    for (int j = 0; j < 4; ++j)
      acc[i][j] = f32x4{0.f, 0.f, 0.f, 0.f};

  u32 rbE[8], rbO[8];
  float snextf[4];
  h2 s2[4];

  STAGE(0, 0);
  STAGE(1, 1);
  LOADB(rbE, 0);
  LOADB(rbO, 1);
  #pragma unroll
  for (int j = 0; j < 4; ++j) snextf[j] = scf[scol[j]];
  asm volatile("s_waitcnt vmcnt(0)" ::: "memory");

  int p0 = 0, p1 = 1, p2 = 2;

  for (int tp = 0; tp < 32; ++tp) {
    const int t0 = 2 * tp;
    const int t1 = t0 + 1;

    asm volatile("s_waitcnt vmcnt(12)" ::: "memory");
    __builtin_amdgcn_s_barrier();
    __builtin_amdgcn_sched_barrier(0);

    #pragma unroll
    for (int j = 0; j < 4; ++j) {
      _Float16 sh = (_Float16)snextf[j];
      s2[j] = h2{sh, sh};
    }
    if (t0 + 2 < 64) STAGE(p2, t0 + 2);

    __builtin_amdgcn_s_setprio(1);
    COMPUTE(rbE, p0);
    __builtin_amdgcn_s_setprio(0);

    if (t0 + 2 < 64) LOADB(rbE, t0 + 2);
    {
      const int gn = (tp + 1 > 31) ? 31 : (tp + 1);
      #pragma unroll
      for (int j = 0; j < 4; ++j) snextf[j] = scf[scol[j] + gn];
    }

    if (tp == 31) {
      asm volatile("s_waitcnt vmcnt(0)" ::: "memory");
    } else {
      asm volatile("s_waitcnt vmcnt(12)" ::: "memory");
    }
    __builtin_amdgcn_s_barrier();
    __builtin_amdgcn_sched_barrier(0);

    if (t1 + 2 < 64) STAGE(p0, t1 + 2);

    __builtin_amdgcn_s_setprio(1);
    COMPUTE(rbO, p1);
    __builtin_amdgcn_s_setprio(0);

    if (t1 + 2 < 64) LOADB(rbO, t1 + 2);

    int tmp = p2; p2 = p1; p1 = p0; p0 = tmp;
  }

  #pragma unroll
  for (int i = 0; i < 8; ++i) {
    int r0 = m0 + i * 16 + (lane >> 4) * 4;
    #pragma unroll
    for (int j = 0; j < 4; ++j) {
      int cc = n0 + wn + j * 16 + ln15;
      #pragma unroll
      for (int r = 0; r < 4; ++r)
        out[(size_t)(r0 + r) * N_DIM + cc] = acc[i][j][r];
    }
  }
#undef STAGE
#undef LOADB
#undef COMPUTE
}

// ---------------------------------------------------------------------------
// SLOW FALLBACK (any mode; skips mode 0 when a fast path ran).
// ---------------------------------------------------------------------------
__global__ __launch_bounds__(256) void q4gemm_slow_kernel(
    const void* __restrict__ xraw,
    const int*  __restrict__ packed,
    const void* __restrict__ scraw,
    float* __restrict__ out,
    const int* __restrict__ modep,
    int skip0)
{
  const int mode = modep ? modep[0] : 0;
  if (skip0 && mode == 0) return;

  __shared__ u16 Asl[128 * LDSK];
  __shared__ u16 Bsl[128 * LDSK];

  const int tid  = threadIdx.x;
  const int lane = tid & 63;
  const int wv   = tid >> 6;
  const int wm   = (wv >> 1) * 64;
  const int wn   = (wv & 1) * 64;
  const int n0   = blockIdx.x * 128;
  const int m0   = blockIdx.y * 128;

  f32x4 acc[4][4];
  #pragma unroll
  for (int i = 0; i < 4; ++i)
    #pragma unroll
    for (int j = 0; j < 4; ++j)
      acc[i][j] = f32x4{0.f, 0.f, 0.f, 0.f};

  const int lrow16 = lane & 15;
  const int lk8    = (lane >> 4) * 8;

  for (int k0 = 0; k0 < K_DIM; k0 += 64) {
    if (mode == 0) {
      const float* xf = (const float*)xraw;
      #pragma unroll
      for (int it = 0; it < 4; ++it) {
        int s = tid + it * 256;
        int row = s >> 3, c8 = (s & 7) * 8;
        const float4* p = (const float4*)(xf + (size_t)(m0 + row) * K_DIM + k0 + c8);
        float4 v0 = p[0], v1 = p[1];
        u16 tmp[8] = { f2bf(v0.x), f2bf(v0.y), f2bf(v0.z), f2bf(v0.w),
                       f2bf(v1.x), f2bf(v1.y), f2bf(v1.z), f2bf(v1.w) };
        *(s16x8*)&Asl[row * LDSK + c8] = *(const s16x8*)tmp;
      }
    } else if (mode == 1) {
      const u16* xhh = (const u16*)xraw;
      #pragma unroll
      for (int it = 0; it < 4; ++it) {
        int s = tid + it * 256;
        int row = s >> 3, c8 = (s & 7) * 8;
        s16x8 v = *(const s16x8*)(xhh + (size_t)(m0 + row) * K_DIM + k0 + c8);
        u16 tmp[8];
        #pragma unroll
        for (int j = 0; j < 8; ++j) tmp[j] = f2bf(h2f((u16)v[j]));
        *(s16x8*)&Asl[row * LDSK + c8] = *(const s16x8*)tmp;
      }
    } else {
      const u16* xhh = (const u16*)xraw;
      #pragma unroll
      for (int it = 0; it < 4; ++it) {
        int s = tid + it * 256;
        int row = s >> 3, c8 = (s & 7) * 8;
        s16x8 v = *(const s16x8*)(xhh + (size_t)(m0 + row) * K_DIM + k0 + c8);
        *(s16x8*)&Asl[row * LDSK + c8] = v;
      }
    }

    {
      int row  = tid >> 1;
      int half = tid & 1;
      int srw  = n0 + row;
      int g    = k0 >> 7;
      float scale;
      if      (mode == 0) scale = ((const float*)scraw)[(size_t)srw * GROUPS + g];
      else if (mode == 1) scale = h2f(((const u16*)scraw)[(size_t)srw * GROUPS + g]);
      else                scale = bf2f(((const u16*)scraw)[(size_t)srw * GROUPS + g]);

      const int4* pp = (const int4*)(packed + (size_t)srw * (K_DIM / 2) + (k0 >> 1) + half * 16);
      #pragma unroll
      for (int j = 0; j < 4; ++j) {
        int4 pv = pp[j];
        int vals[4] = {pv.x, pv.y, pv.z, pv.w};
        u16 w[8];
        #pragma unroll
        for (int e = 0; e < 4; ++e) {
          int b = vals[e] & 255;
          w[e * 2]     = f2bf(scale * (float)((b & 15) - 8));
          w[e * 2 + 1] = f2bf(scale * (float)(((b >> 4) & 15) - 8));
        }
        int i0 = half * 16 + j * 4;
        *(s16x8*)&Bsl[row * LDSK + i0 * 2] = *(const s16x8*)w;
      }
    }
    __syncthreads();

    #pragma unroll
    for (int kk = 0; kk < 64; kk += 32) {
      s16x8 af[4], bfr[4];
      int klane = kk + lk8;
      #pragma unroll
      for (int i = 0; i < 4; ++i)
        af[i] = *(const s16x8*)&Asl[(wm + i * 16 + lrow16) * LDSK + klane];
      #pragma unroll
      for (int i = 0; i < 4; ++i)
        bfr[i] = *(const s16x8*)&Bsl[(wn + i * 16 + lrow16) * LDSK + klane];
      #pragma unroll
      for (int i = 0; i < 4; ++i)
        #pragma unroll
        for (int j = 0; j < 4; ++j)
          acc[i][j] = __builtin_amdgcn_mfma_f32_16x16x32_bf16(af[i], bfr[j], acc[i][j], 0, 0, 0);
    }
    __syncthreads();
  }

  #pragma unroll
  for (int i = 0; i < 4; ++i) {
    int rbase = m0 + wm + i * 16 + ((lane >> 4) * 4);
    #pragma unroll
    for (int j = 0; j < 4; ++j) {
      int c = n0 + wn + j * 16 + (lane & 15);
      #pragma unroll
      for (int r = 0; r < 4; ++r)
        out[(size_t)(rbase + r) * N_DIM + c] = acc[i][j][r];
    }
  }
}

extern "C" void kernel_launch(void* const* d_in, const int* in_sizes, int n_in,
                              void* d_out, int out_size, void* d_ws, size_t ws_size,
                              hipStream_t stream) {
  const void* x      = d_in[0];
  const int*  packed = (const int*)d_in[1];
  const void* scales = d_in[2];
  float* out = (float*)d_out;

  const size_t XB = (size_t)M_DIM * K_DIM * 2;        // 67,108,864 B
  const size_t WF = (size_t)N_DIM * K_DIM * 2;        // 90,177,536 B
  const size_t WQ = (size_t)N_DIM * WQROW * 4;        // 22,544,384 B
  const size_t NEED_BIG = 256 + XB + WF;              // ~157.3 MB
  const size_t NEED_MID = 256 + XB + WQ;              // ~89.7 MB

  int* mode_flag = nullptr;
  if (ws_size >= 4) {
    mode_flag = (int*)d_ws;
    probe_mode_kernel<<<dim3(1), dim3(256), 0, stream>>>(scales, mode_flag);
  }

  int fast = 0;
  if (mode_flag && ws_size >= NEED_BIG) fast = 2;
  else if (mode_flag && ws_size >= NEED_MID) fast = 1;

  if (fast == 2) {
    u16* xh = (u16*)((char*)d_ws + 256);
    u16* wf = (u16*)((char*)d_ws + 256 + XB);
    convert_x_nat_kernel<<<dim3(2048), dim3(256), 0, stream>>>(
        (const float*)x, xh, mode_flag);
    dequant_w_kernel<<<dim3(2048), dim3(256), 0, stream>>>(
        packed, (const float*)scales, wf, mode_flag);
    q4gemm_big_kernel<<<dim3(1376), dim3(512), 0, stream>>>(
        xh, wf, out, mode_flag);
  } else if (fast == 1) {
    u16* xh = (u16*)((char*)d_ws + 256);
    u32* wq = (u32*)((char*)d_ws + 256 + XB);
    convert_x_perm_kernel<<<dim3(2048), dim3(256), 0, stream>>>(
        (const float*)x, xh, mode_flag);
    repack_w_kernel<<<dim3(2048), dim3(256), 0, stream>>>(packed, wq);
    q4gemm_mid_kernel<<<dim3(2752), dim3(256), 0, stream>>>(
        xh, wq, (const float*)scales, out, mode_flag);
  }

  q4gemm_slow_kernel<<<dim3(N_DIM / 128, M_DIM / 128), dim3(256), 0, stream>>>(
      x, packed, scales, out, mode_flag, fast);
}

// Round 15
// 839.288 us; speedup vs baseline: 1.1525x; 1.1525x over previous
//
#include <hip/hip_runtime.h>

#define M_DIM 8192
#define N_DIM 11008
#define K_DIM 4096
#define GROUPS 32     // K / 128
#define WQROW 512     // dwords per row of compact W = K/8
#define LDSK 72       // slow kernel pad

typedef short s16x8 __attribute__((ext_vector_type(8)));
typedef _Float16 f16x8 __attribute__((ext_vector_type(8)));
typedef _Float16 h2 __attribute__((ext_vector_type(2)));
typedef float f32x4 __attribute__((ext_vector_type(4)));
typedef unsigned short u16;
typedef unsigned int u32;

union f32u { float f; unsigned u; };
union h16u { u16 u; _Float16 h; };

__device__ __forceinline__ u16 f2bf(float f) {
  f32u v; v.f = f;
  unsigned r = v.u + 0x7FFFu + ((v.u >> 16) & 1u);  // RNE
  return (u16)(r >> 16);
}
__device__ __forceinline__ float bf2f(u16 b) {
  f32u v; v.u = ((unsigned)b) << 16; return v.f;
}
__device__ __forceinline__ float h2f(u16 b) {
  h16u v; v.u = b; return (float)v.h;
}

// ---------------------------------------------------------------------------
// Probe (R3/R4 empirics: harness promotes fp16 -> f32 => mode 0).
// ---------------------------------------------------------------------------
__global__ void probe_mode_kernel(const void* __restrict__ scales,
                                  int* __restrict__ mode_out) {
  __shared__ int cnt[3];
  int t = threadIdx.x;
  if (t < 3) cnt[t] = 0;
  __syncthreads();
  float f0 = ((const float*)scales)[t];
  u16  hu  = ((const u16*)scales)[t];
  float f1 = h2f(hu);
  float f2 = bf2f(hu);
  if (f0 > 0.0004f && f0 < 0.065f) atomicAdd(&cnt[0], 1);
  if (f1 > 0.0004f && f1 < 0.065f) atomicAdd(&cnt[1], 1);
  if (f2 > 0.0004f && f2 < 0.065f) atomicAdd(&cnt[2], 1);
  __syncthreads();
  if (t == 0) {
    int m;
    if      (cnt[1] >= 240) m = 1;
    else if (cnt[2] >= 240) m = 2;
    else                    m = 0;
    mode_out[0] = m;
  }
}

// ---------------------------------------------------------------------------
// BIG-PATH pre-pass 1: x f32 -> fp16, NATURAL order (exact).
// ---------------------------------------------------------------------------
__global__ __launch_bounds__(256) void convert_x_nat_kernel(
    const float* __restrict__ xf, u16* __restrict__ xh,
    const int* __restrict__ modep) {
  if (modep && modep[0] != 0) return;
  const int total8 = M_DIM * (K_DIM / 8);
  int idx = blockIdx.x * 256 + threadIdx.x;
  const int stride = gridDim.x * 256;
  for (; idx < total8; idx += stride) {
    const float4* p = (const float4*)(xf + (size_t)idx * 8);
    float4 a = p[0], b = p[1];
    union { _Float16 h[8]; s16x8 v; } r;
    r.h[0] = (_Float16)a.x; r.h[1] = (_Float16)a.y;
    r.h[2] = (_Float16)a.z; r.h[3] = (_Float16)a.w;
    r.h[4] = (_Float16)b.x; r.h[5] = (_Float16)b.y;
    r.h[6] = (_Float16)b.z; r.h[7] = (_Float16)b.w;
    *(s16x8*)(xh + (size_t)idx * 8) = r.v;
  }
}

// ---------------------------------------------------------------------------
// BIG-PATH pre-pass 2: full dequant W -> fp16 [N][K], natural order.
// ---------------------------------------------------------------------------
__global__ __launch_bounds__(256) void dequant_w_kernel(
    const int* __restrict__ packed, const float* __restrict__ scf,
    u16* __restrict__ wf, const int* __restrict__ modep) {
  if (modep && modep[0] != 0) return;
  const int total = N_DIM * (K_DIM / 8);    // 5,636,096 chunks
  int idx = blockIdx.x * 256 + threadIdx.x;
  const int stride = gridDim.x * 256;
  for (; idx < total; idx += stride) {
    const int col = idx >> 9;               // K/8 = 512 chunks per row
    const int d   = idx & 511;
    const float s = scf[col * GROUPS + (d >> 4)];
    const int4 p  = ((const int4*)packed)[idx];
    const int vals[4] = {p.x, p.y, p.z, p.w};
    union { _Float16 h[8]; s16x8 v; } r;
    #pragma unroll
    for (int e = 0; e < 4; ++e) {
      int b = vals[e] & 255;
      r.h[2 * e]     = (_Float16)((float)((b & 15) - 8) * s);
      r.h[2 * e + 1] = (_Float16)((float)(((b >> 4) & 15) - 8) * s);
    }
    *(s16x8*)(wf + (size_t)idx * 8) = r.v;
  }
}

// ---------------------------------------------------------------------------
// BIG-PATH GEMM (R15): 256x256 block, 8 waves (2m x 4n), BK=64.
// R14 post-mortem: per-sub-phase barriers serialized the LDS pipe against
// the matrix pipe (2483 MFMA + 2770 LDS + sync = 6800 cyc/tile measured).
// R15: ONE barrier per tile (buffer generation only); fragment ds_reads are
// software-pipelined one sub-phase deep (loads for s+1 issue before MFMA of
// s, sched_barrier(0)-pinned; compiler emits its own counted lgkmcnt) so
// LDS reads overlap MFMA. Race ledger: intra-tile reads all hit buf(cur)
// staged last tile (entry vmcnt(0)+barrier); stages write buf(cur^1) only;
// every wave's ds_reads are consumed by in-tile MFMAs (compiler waits), so
// its reads are drained before it crosses the next entry barrier.
// ---------------------------------------------------------------------------
__global__ __launch_bounds__(512, 2) void q4gemm_big_kernel(
    const u16* __restrict__ xh,      // fp16 natural [M][K]
    const u16* __restrict__ wf,      // fp16 W [N][K]
    float* __restrict__ out,
    const int* __restrict__ modep)
{
  if (modep && modep[0] != 0) return;

  __shared__ _Float16 AsA[2][256 * 64];   // 64 KiB
  __shared__ _Float16 AsB[2][256 * 64];   // 64 KiB

  const int tid  = threadIdx.x;
  const int lane = tid & 63;
  const int wv   = tid >> 6;             // 0..7
  const int wm   = (wv >> 2) * 128;      // 2 waves in m
  const int wn   = (wv & 3) * 64;        // 4 waves in n
  const int ln15 = lane & 15;
  const int lk   = lane >> 4;            // 0..3

  // XCD swizzle: 1376 = 8 * 172; per-XCD contiguous f, bm-fastest within a
  // bn group -> same-XCD neighbors share the 2MB B panel.
  int bid = blockIdx.x;
  int f   = (bid & 7) * 172 + (bid >> 3);
  int bn  = f / 32;                      // 0..42
  int bm  = f - bn * 32;                 // 0..31
  const int m0 = bm * 256;
  const int n0 = bn * 256;

  // Staging addresses: LDS[row][slot] = G[row][slot ^ (row&7)] (16B chunks).
  const int srow  = lane >> 3;           // 0..7
  const int sperm = (lane & 7) ^ srow;
  const u16* abase[4];
  const u16* bbase[4];
  #pragma unroll
  for (int q = 0; q < 4; ++q) {
    int row = q * 64 + wv * 8 + srow;
    abase[q] = xh + (size_t)(m0 + row) * K_DIM + sperm * 8;
    bbase[q] = wf + (size_t)(n0 + row) * K_DIM + sperm * 8;
  }

#define STAGE_ALL(PB, T) do { \
    _Float16* da = &AsA[(PB)][0]; \
    _Float16* db = &AsB[(PB)][0]; \
    _Pragma("unroll") \
    for (int q = 0; q < 4; ++q) \
      __builtin_amdgcn_global_load_lds( \
          (const __attribute__((address_space(1))) void*)(abase[q] + (T) * 64), \
          (__attribute__((address_space(3))) void*)(da + q * 4096 + wv * 512), \
          16, 0, 0); \
    _Pragma("unroll") \
    for (int q = 0; q < 4; ++q) \
      __builtin_amdgcn_global_load_lds( \
          (const __attribute__((address_space(1))) void*)(bbase[q] + (T) * 64), \
          (__attribute__((address_space(3))) void*)(db + q * 4096 + wv * 512), \
          16, 0, 0); \
  } while (0)

#define LOAD_AF(DST, IH, SLOT) do { \
    _Pragma("unroll") \
    for (int ii = 0; ii < 4; ++ii) { \
      int r = wm + ((IH) * 4 + ii) * 16 + ln15; \
      DST[ii] = *(const f16x8*)&Ab[r * 64 + (SLOT) * 8]; \
    } \
  } while (0)

#define LOAD_BF(DST, SLOT) do { \
    _Pragma("unroll") \
    for (int j = 0; j < 4; ++j) { \
      int r = wn + j * 16 + ln15; \
      DST[j] = *(const f16x8*)&Bb[r * 64 + (SLOT) * 8]; \
    } \
  } while (0)

#define MFMA16(AF, BF, IH) do { \
    __builtin_amdgcn_s_setprio(1); \
    _Pragma("unroll") \
    for (int ii = 0; ii < 4; ++ii) { \
      acc[(IH) * 4 + ii][0] = __builtin_amdgcn_mfma_f32_16x16x32_f16(AF[ii], BF[0], acc[(IH) * 4 + ii][0], 0, 0, 0); \
      acc[(IH) * 4 + ii][1] = __builtin_amdgcn_mfma_f32_16x16x32_f16(AF[ii], BF[1], acc[(IH) * 4 + ii][1], 0, 0, 0); \
      acc[(IH) * 4 + ii][2] = __builtin_amdgcn_mfma_f32_16x16x32_f16(AF[ii], BF[2], acc[(IH) * 4 + ii][2], 0, 0, 0); \
      acc[(IH) * 4 + ii][3] = __builtin_amdgcn_mfma_f32_16x16x32_f16(AF[ii], BF[3], acc[(IH) * 4 + ii][3], 0, 0, 0); \
    } \
    __builtin_amdgcn_s_setprio(0); \
  } while (0)

  f32x4 acc[8][4];
  #pragma unroll
  for (int i = 0; i < 8; ++i)
    #pragma unroll
    for (int j = 0; j < 4; ++j)
      acc[i][j] = f32x4{0.f, 0.f, 0.f, 0.f};

  // prologue: stage tile 0 into buf 0
  STAGE_ALL(0, 0);

  #pragma unroll 1
  for (int t = 0; t < 64; ++t) {
    const int cur = t & 1;

    // tile entry: stages of tile t (only outstanding vmem) landed
    asm volatile("s_waitcnt vmcnt(0)" ::: "memory");
    __builtin_amdgcn_s_barrier();

    // prefetch tile t+1 (full tile of slack before its vmcnt(0))
    if (t < 63) STAGE_ALL(cur ^ 1, t + 1);

    const _Float16* Ab = &AsA[cur][0];
    const _Float16* Bb = &AsB[cur][0];
    const int slotx = ln15 & 7;
    const int slot0 = lk ^ slotx;            // kkc = 0
    const int slot1 = (4 + lk) ^ slotx;      // kkc = 1

    f16x8 bf0[4], bf1[4], afA[4], afB[4];

    // ---- pipelined sub-phases: loads(s+1) issue before MFMA(s) ----
    LOAD_BF(bf0, slot0);          // s0 data
    LOAD_AF(afA, 0, slot0);
    LOAD_AF(afB, 1, slot0);       // s1 data (prefetch)
    __builtin_amdgcn_sched_barrier(0);
    MFMA16(afA, bf0, 0);          // s0
    LOAD_BF(bf1, slot1);          // s2 data (prefetch)
    LOAD_AF(afA, 0, slot1);
    __builtin_amdgcn_sched_barrier(0);
    MFMA16(afB, bf0, 1);          // s1
    LOAD_AF(afB, 1, slot1);       // s3 data (prefetch)
    __builtin_amdgcn_sched_barrier(0);
    MFMA16(afA, bf1, 0);          // s2
    __builtin_amdgcn_sched_barrier(0);
    MFMA16(afB, bf1, 1);          // s3
  }

  // epilogue: C/D col=lane&15, row=(lane>>4)*4+reg — nontemporal stores.
  #pragma unroll
  for (int i = 0; i < 8; ++i) {
    int r0 = m0 + wm + i * 16 + (lane >> 4) * 4;
    #pragma unroll
    for (int j = 0; j < 4; ++j) {
      int cc = n0 + wn + j * 16 + ln15;
      #pragma unroll
      for (int r = 0; r < 4; ++r)
        __builtin_nontemporal_store(acc[i][j][r], &out[(size_t)(r0 + r) * N_DIM + cc]);
    }
  }
#undef STAGE_ALL
#undef LOAD_AF
#undef LOAD_BF
#undef MFMA16
}

// ---------------------------------------------------------------------------
// MID PATH (R10 verified; runs only if ws fits 90MB but not 157MB).
// ---------------------------------------------------------------------------
__global__ __launch_bounds__(256) void convert_x_perm_kernel(
    const float* __restrict__ xf, u16* __restrict__ xh,
    const int* __restrict__ modep) {
  if (modep && modep[0] != 0) return;
  const int total8 = M_DIM * (K_DIM / 8);
  int idx = blockIdx.x * 256 + threadIdx.x;
  const int stride = gridDim.x * 256;
  for (; idx < total8; idx += stride) {
    const float4* p = (const float4*)(xf + (size_t)idx * 8);
    float4 a = p[0], b = p[1];
    union { _Float16 h[8]; s16x8 v; } r;
    r.h[0] = (_Float16)a.x; r.h[1] = (_Float16)b.x;
    r.h[2] = (_Float16)a.y; r.h[3] = (_Float16)b.y;
    r.h[4] = (_Float16)a.z; r.h[5] = (_Float16)b.z;
    r.h[6] = (_Float16)a.w; r.h[7] = (_Float16)b.w;
    *(s16x8*)(xh + (size_t)idx * 8) = r.v;
  }
}

__global__ __launch_bounds__(256) void repack_w_kernel(
    const int* __restrict__ packed, u32* __restrict__ wq) {
  const int total = N_DIM * WQROW;
  int idx = blockIdx.x * 256 + threadIdx.x;
  const int stride = gridDim.x * 256;
  for (; idx < total; idx += stride) {
    const int4 p = ((const int4*)packed)[idx];
    wq[idx] = (u32)(p.x & 255) | ((u32)(p.y & 255) << 8) |
              ((u32)(p.z & 255) << 16) | ((u32)p.w << 24);
  }
}

__device__ __forceinline__ f16x8 dq8(u32 q, h2 s2) {
  const u32 M = 0x000F000Fu, G = 0x64006400u;
  const h2 bias = {(_Float16)(-1032.0f), (_Float16)(-1032.0f)};
  union { u32 u; h2 h; } a0, a1, a2, a3;
  a0.u = (q & M) | G;
  a1.u = ((q >> 4) & M) | G;
  a2.u = ((q >> 8) & M) | G;
  a3.u = ((q >> 12) & M) | G;
  a0.h = (a0.h + bias) * s2;
  a1.h = (a1.h + bias) * s2;
  a2.h = (a2.h + bias) * s2;
  a3.h = (a3.h + bias) * s2;
  union { u32 u[4]; f16x8 f; } r;
  r.u[0] = a0.u; r.u[1] = a1.u; r.u[2] = a2.u; r.u[3] = a3.u;
  return r.f;
}

__global__ __launch_bounds__(256, 2) void q4gemm_mid_kernel(
    const u16* __restrict__ xh, const u32* __restrict__ wq,
    const float* __restrict__ scf, float* __restrict__ out,
    const int* __restrict__ modep)
{
  if (modep && modep[0] != 0) return;

  __shared__ _Float16 As[3][128 * 64];

  const int tid  = threadIdx.x;
  const int lane = tid & 63;
  const int wv   = tid >> 6;
  const int wn   = wv * 64;
  const int ln15 = lane & 15;
  const int lk   = lane >> 4;

  int bid = blockIdx.x;
  int f   = (bid & 7) * 344 + (bid >> 3);
  int bn  = f / 64;
  int bm  = f - bn * 64;
  const int m0 = bm * 128;
  const int n0 = bn * 256;

  const u16* abase[4];
  #pragma unroll
  for (int q = 0; q < 4; ++q) {
    int row = q * 32 + wv * 8 + (lane >> 3);
    abase[q] = xh + (size_t)(m0 + row) * K_DIM + (((lane & 7) ^ (lane >> 3)) * 8);
  }

#define STAGE(PB, T) do { \
    _Float16* dst = &As[(PB)][0]; \
    _Pragma("unroll") \
    for (int q = 0; q < 4; ++q) \
      __builtin_amdgcn_global_load_lds( \
          (const __attribute__((address_space(1))) void*)(abase[q] + (T) * 64), \
          (__attribute__((address_space(3))) void*)(dst + q * 2048 + wv * 512), \
          16, 0, 0); \
  } while (0)

#define LOADB(RB, T) do { \
    _Pragma("unroll") \
    for (int j = 0; j < 4; ++j) { \
      RB[j]     = wq[pcol[j] + (T) * 8]; \
      RB[j + 4] = wq[pcol[j] + (T) * 8 + 4]; \
    } \
  } while (0)

#define COMPUTE(RB, PB) do { \
    const _Float16* asb = &As[(PB)][0]; \
    _Pragma("unroll") \
    for (int kkc = 0; kkc < 2; ++kkc) { \
      f16x8 bfr0 = dq8(RB[kkc * 4 + 0], s2[0]); \
      f16x8 bfr1 = dq8(RB[kkc * 4 + 1], s2[1]); \
      f16x8 bfr2 = dq8(RB[kkc * 4 + 2], s2[2]); \
      f16x8 bfr3 = dq8(RB[kkc * 4 + 3], s2[3]); \
      _Pragma("unroll") \
      for (int i = 0; i < 8; ++i) { \
        const int row  = i * 16 + ln15; \
        const int slot = (kkc * 4 + lk) ^ (ln15 & 7); \
        f16x8 af = *(const f16x8*)&asb[row * 64 + slot * 8]; \
        acc[i][0] = __builtin_amdgcn_mfma_f32_16x16x32_f16(af, bfr0, acc[i][0], 0, 0, 0); \
        acc[i][1] = __builtin_amdgcn_mfma_f32_16x16x32_f16(af, bfr1, acc[i][1], 0, 0, 0); \
        acc[i][2] = __builtin_amdgcn_mfma_f32_16x16x32_f16(af, bfr2, acc[i][2], 0, 0, 0); \
        acc[i][3] = __builtin_amdgcn_mfma_f32_16x16x32_f16(af, bfr3, acc[i][3], 0, 0, 0); \
      } \
    } \
  } while (0)

  int pcol[4], scol[4];
  #pragma unroll
  for (int j = 0; j < 4; ++j) {
    int col = n0 + wn + j * 16 + ln15;
    pcol[j] = col * WQROW + lk;
    scol[j] = col * GROUPS;
  }

  f32x4 acc[8][4];
  #pragma unroll
  for (int i = 0; i < 8; ++i)
    #pragma unroll
    for (int j = 0; j < 4; ++j)
      acc[i][j] = f32x4{0.f, 0.f, 0.f, 0.f};

  u32 rbE[8], rbO[8];
  float snextf[4];
  h2 s2[4];

  STAGE(0, 0);
  STAGE(1, 1);
  LOADB(rbE, 0);
  LOADB(rbO, 1);
  #pragma unroll
  for (int j = 0; j < 4; ++j) snextf[j] = scf[scol[j]];
  asm volatile("s_waitcnt vmcnt(0)" ::: "memory");

  int p0 = 0, p1 = 1, p2 = 2;

  for (int tp = 0; tp < 32; ++tp) {
    const int t0 = 2 * tp;
    const int t1 = t0 + 1;

    asm volatile("s_waitcnt vmcnt(12)" ::: "memory");
    __builtin_amdgcn_s_barrier();
    __builtin_amdgcn_sched_barrier(0);

    #pragma unroll
    for (int j = 0; j < 4; ++j) {
      _Float16 sh = (_Float16)snextf[j];
      s2[j] = h2{sh, sh};
    }
    if (t0 + 2 < 64) STAGE(p2, t0 + 2);

    __builtin_amdgcn_s_setprio(1);
    COMPUTE(rbE, p0);
    __builtin_amdgcn_s_setprio(0);

    if (t0 + 2 < 64) LOADB(rbE, t0 + 2);
    {
      const int gn = (tp + 1 > 31) ? 31 : (tp + 1);
      #pragma unroll
      for (int j = 0; j < 4; ++j) snextf[j] = scf[scol[j] + gn];
    }

    if (tp == 31) {
      asm volatile("s_waitcnt vmcnt(0)" ::: "memory");
    } else {
      asm volatile("s_waitcnt vmcnt(12)" ::: "memory");
    }
    __builtin_amdgcn_s_barrier();
    __builtin_amdgcn_sched_barrier(0);

    if (t1 + 2 < 64) STAGE(p0, t1 + 2);

    __builtin_amdgcn_s_setprio(1);
    COMPUTE(rbO, p1);
    __builtin_amdgcn_s_setprio(0);

    if (t1 + 2 < 64) LOADB(rbO, t1 + 2);

    int tmp = p2; p2 = p1; p1 = p0; p0 = tmp;
  }

  #pragma unroll
  for (int i = 0; i < 8; ++i) {
    int r0 = m0 + i * 16 + (lane >> 4) * 4;
    #pragma unroll
    for (int j = 0; j < 4; ++j) {
      int cc = n0 + wn + j * 16 + ln15;
      #pragma unroll
      for (int r = 0; r < 4; ++r)
        out[(size_t)(r0 + r) * N_DIM + cc] = acc[i][j][r];
    }
  }
#undef STAGE
#undef LOADB
#undef COMPUTE
}

// ---------------------------------------------------------------------------
// SLOW FALLBACK (any mode; skips mode 0 when a fast path ran).
// ---------------------------------------------------------------------------
__global__ __launch_bounds__(256) void q4gemm_slow_kernel(
    const void* __restrict__ xraw,
    const int*  __restrict__ packed,
    const void* __restrict__ scraw,
    float* __restrict__ out,
    const int* __restrict__ modep,
    int skip0)
{
  const int mode = modep ? modep[0] : 0;
  if (skip0 && mode == 0) return;

  __shared__ u16 Asl[128 * LDSK];
  __shared__ u16 Bsl[128 * LDSK];

  const int tid  = threadIdx.x;
  const int lane = tid & 63;
  const int wv   = tid >> 6;
  const int wm   = (wv >> 1) * 64;
  const int wn   = (wv & 1) * 64;
  const int n0   = blockIdx.x * 128;
  const int m0   = blockIdx.y * 128;

  f32x4 acc[4][4];
  #pragma unroll
  for (int i = 0; i < 4; ++i)
    #pragma unroll
    for (int j = 0; j < 4; ++j)
      acc[i][j] = f32x4{0.f, 0.f, 0.f, 0.f};

  const int lrow16 = lane & 15;
  const int lk8    = (lane >> 4) * 8;

  for (int k0 = 0; k0 < K_DIM; k0 += 64) {
    if (mode == 0) {
      const float* xf = (const float*)xraw;
      #pragma unroll
      for (int it = 0; it < 4; ++it) {
        int s = tid + it * 256;
        int row = s >> 3, c8 = (s & 7) * 8;
        const float4* p = (const float4*)(xf + (size_t)(m0 + row) * K_DIM + k0 + c8);
        float4 v0 = p[0], v1 = p[1];
        u16 tmp[8] = { f2bf(v0.x), f2bf(v0.y), f2bf(v0.z), f2bf(v0.w),
                       f2bf(v1.x), f2bf(v1.y), f2bf(v1.z), f2bf(v1.w) };
        *(s16x8*)&Asl[row * LDSK + c8] = *(const s16x8*)tmp;
      }
    } else if (mode == 1) {
      const u16* xhh = (const u16*)xraw;
      #pragma unroll
      for (int it = 0; it < 4; ++it) {
        int s = tid + it * 256;
        int row = s >> 3, c8 = (s & 7) * 8;
        s16x8 v = *(const s16x8*)(xhh + (size_t)(m0 + row) * K_DIM + k0 + c8);
        u16 tmp[8];
        #pragma unroll
        for (int j = 0; j < 8; ++j) tmp[j] = f2bf(h2f((u16)v[j]));
        *(s16x8*)&Asl[row * LDSK + c8] = *(const s16x8*)tmp;
      }
    } else {
      const u16* xhh = (const u16*)xraw;
      #pragma unroll
      for (int it = 0; it < 4; ++it) {
        int s = tid + it * 256;
        int row = s >> 3, c8 = (s & 7) * 8;
        s16x8 v = *(const s16x8*)(xhh + (size_t)(m0 + row) * K_DIM + k0 + c8);
        *(s16x8*)&Asl[row * LDSK + c8] = v;
      }
    }

    {
      int row  = tid >> 1;
      int half = tid & 1;
      int srw  = n0 + row;
      int g    = k0 >> 7;
      float scale;
      if      (mode == 0) scale = ((const float*)scraw)[(size_t)srw * GROUPS + g];
      else if (mode == 1) scale = h2f(((const u16*)scraw)[(size_t)srw * GROUPS + g]);
      else                scale = bf2f(((const u16*)scraw)[(size_t)srw * GROUPS + g]);

      const int4* pp = (const int4*)(packed + (size_t)srw * (K_DIM / 2) + (k0 >> 1) + half * 16);
      #pragma unroll
      for (int j = 0; j < 4; ++j) {
        int4 pv = pp[j];
        int vals[4] = {pv.x, pv.y, pv.z, pv.w};
        u16 w[8];
        #pragma unroll
        for (int e = 0; e < 4; ++e) {
          int b = vals[e] & 255;
          w[e * 2]     = f2bf(scale * (float)((b & 15) - 8));
          w[e * 2 + 1] = f2bf(scale * (float)(((b >> 4) & 15) - 8));
        }
        int i0 = half * 16 + j * 4;
        *(s16x8*)&Bsl[row * LDSK + i0 * 2] = *(const s16x8*)w;
      }
    }
    __syncthreads();

    #pragma unroll
    for (int kk = 0; kk < 64; kk += 32) {
      s16x8 af[4], bfr[4];
      int klane = kk + lk8;
      #pragma unroll
      for (int i = 0; i < 4; ++i)
        af[i] = *(const s16x8*)&Asl[(wm + i * 16 + lrow16) * LDSK + klane];
      #pragma unroll
      for (int i = 0; i < 4; ++i)
        bfr[i] = *(const s16x8*)&Bsl[(wn + i * 16 + lrow16) * LDSK + klane];
      #pragma unroll
      for (int i = 0; i < 4; ++i)
        #pragma unroll
        for (int j = 0; j < 4; ++j)
          acc[i][j] = __builtin_amdgcn_mfma_f32_16x16x32_bf16(af[i], bfr[j], acc[i][j], 0, 0, 0);
    }
    __syncthreads();
  }

  #pragma unroll
  for (int i = 0; i < 4; ++i) {
    int rbase = m0 + wm + i * 16 + ((lane >> 4) * 4);
    #pragma unroll
    for (int j = 0; j < 4; ++j) {
      int c = n0 + wn + j * 16 + (lane & 15);
      #pragma unroll
      for (int r = 0; r < 4; ++r)
        out[(size_t)(rbase + r) * N_DIM + c] = acc[i][j][r];
    }
  }
}

extern "C" void kernel_launch(void* const* d_in, const int* in_sizes, int n_in,
                              void* d_out, int out_size, void* d_ws, size_t ws_size,
                              hipStream_t stream) {
  const void* x      = d_in[0];
  const int*  packed = (const int*)d_in[1];
  const void* scales = d_in[2];
  float* out = (float*)d_out;

  const size_t XB = (size_t)M_DIM * K_DIM * 2;        // 67,108,864 B
  const size_t WF = (size_t)N_DIM * K_DIM * 2;        // 90,177,536 B
  const size_t WQ = (size_t)N_DIM * WQROW * 4;        // 22,544,384 B
  const size_t NEED_BIG = 256 + XB + WF;              // ~157.3 MB
  const size_t NEED_MID = 256 + XB + WQ;              // ~89.7 MB

  int* mode_flag = nullptr;
  if (ws_size >= 4) {
    mode_flag = (int*)d_ws;
    probe_mode_kernel<<<dim3(1), dim3(256), 0, stream>>>(scales, mode_flag);
  }

  int fast = 0;
  if (mode_flag && ws_size >= NEED_BIG) fast = 2;
  else if (mode_flag && ws_size >= NEED_MID) fast = 1;

  if (fast == 2) {
    u16* xh = (u16*)((char*)d_ws + 256);
    u16* wf = (u16*)((char*)d_ws + 256 + XB);
    convert_x_nat_kernel<<<dim3(2048), dim3(256), 0, stream>>>(
        (const float*)x, xh, mode_flag);
    dequant_w_kernel<<<dim3(2048), dim3(256), 0, stream>>>(
        packed, (const float*)scales, wf, mode_flag);
    q4gemm_big_kernel<<<dim3(1376), dim3(512), 0, stream>>>(
        xh, wf, out, mode_flag);
  } else if (fast == 1) {
    u16* xh = (u16*)((char*)d_ws + 256);
    u32* wq = (u32*)((char*)d_ws + 256 + XB);
    convert_x_perm_kernel<<<dim3(2048), dim3(256), 0, stream>>>(
        (const float*)x, xh, mode_flag);
    repack_w_kernel<<<dim3(2048), dim3(256), 0, stream>>>(packed, wq);
    q4gemm_mid_kernel<<<dim3(2752), dim3(256), 0, stream>>>(
        xh, wq, (const float*)scales, out, mode_flag);
  }

  q4gemm_slow_kernel<<<dim3(N_DIM / 128, M_DIM / 128), dim3(256), 0, stream>>>(
      x, packed, scales, out, mode_flag, fast);
}

// Round 16
// 829.219 us; speedup vs baseline: 1.1665x; 1.0121x over previous
//
#include <hip/hip_runtime.h>

#define M_DIM 8192
#define N_DIM 11008
#define K_DIM 4096
#define GROUPS 32     // K / 128
#define WQROW 512     // dwords per row of compact W = K/8
#define LDSK 72       // slow kernel pad

typedef short s16x8 __attribute__((ext_vector_type(8)));
typedef _Float16 f16x8 __attribute__((ext_vector_type(8)));
typedef _Float16 h2 __attribute__((ext_vector_type(2)));
typedef float f32x4 __attribute__((ext_vector_type(4)));
typedef unsigned short u16;
typedef unsigned int u32;

union f32u { float f; unsigned u; };
union h16u { u16 u; _Float16 h; };

__device__ __forceinline__ u16 f2bf(float f) {
  f32u v; v.f = f;
  unsigned r = v.u + 0x7FFFu + ((v.u >> 16) & 1u);  // RNE
  return (u16)(r >> 16);
}
__device__ __forceinline__ float bf2f(u16 b) {
  f32u v; v.u = ((unsigned)b) << 16; return v.f;
}
__device__ __forceinline__ float h2f(u16 b) {
  h16u v; v.u = b; return (float)v.h;
}

// ---------------------------------------------------------------------------
// Probe (R3/R4 empirics: harness promotes fp16 -> f32 => mode 0).
// ---------------------------------------------------------------------------
__global__ void probe_mode_kernel(const void* __restrict__ scales,
                                  int* __restrict__ mode_out) {
  __shared__ int cnt[3];
  int t = threadIdx.x;
  if (t < 3) cnt[t] = 0;
  __syncthreads();
  float f0 = ((const float*)scales)[t];
  u16  hu  = ((const u16*)scales)[t];
  float f1 = h2f(hu);
  float f2 = bf2f(hu);
  if (f0 > 0.0004f && f0 < 0.065f) atomicAdd(&cnt[0], 1);
  if (f1 > 0.0004f && f1 < 0.065f) atomicAdd(&cnt[1], 1);
  if (f2 > 0.0004f && f2 < 0.065f) atomicAdd(&cnt[2], 1);
  __syncthreads();
  if (t == 0) {
    int m;
    if      (cnt[1] >= 240) m = 1;
    else if (cnt[2] >= 240) m = 2;
    else                    m = 0;
    mode_out[0] = m;
  }
}

// ---------------------------------------------------------------------------
// BIG-PATH pre-pass 1: x f32 -> fp16, NATURAL order (exact).
// ---------------------------------------------------------------------------
__global__ __launch_bounds__(256) void convert_x_nat_kernel(
    const float* __restrict__ xf, u16* __restrict__ xh,
    const int* __restrict__ modep) {
  if (modep && modep[0] != 0) return;
  const int total8 = M_DIM * (K_DIM / 8);
  int idx = blockIdx.x * 256 + threadIdx.x;
  const int stride = gridDim.x * 256;
  for (; idx < total8; idx += stride) {
    const float4* p = (const float4*)(xf + (size_t)idx * 8);
    float4 a = p[0], b = p[1];
    union { _Float16 h[8]; s16x8 v; } r;
    r.h[0] = (_Float16)a.x; r.h[1] = (_Float16)a.y;
    r.h[2] = (_Float16)a.z; r.h[3] = (_Float16)a.w;
    r.h[4] = (_Float16)b.x; r.h[5] = (_Float16)b.y;
    r.h[6] = (_Float16)b.z; r.h[7] = (_Float16)b.w;
    *(s16x8*)(xh + (size_t)idx * 8) = r.v;
  }
}

// ---------------------------------------------------------------------------
// BIG-PATH pre-pass 2: full dequant W -> fp16 [N][K], natural order.
// ---------------------------------------------------------------------------
__global__ __launch_bounds__(256) void dequant_w_kernel(
    const int* __restrict__ packed, const float* __restrict__ scf,
    u16* __restrict__ wf, const int* __restrict__ modep) {
  if (modep && modep[0] != 0) return;
  const int total = N_DIM * (K_DIM / 8);    // 5,636,096 chunks
  int idx = blockIdx.x * 256 + threadIdx.x;
  const int stride = gridDim.x * 256;
  for (; idx < total; idx += stride) {
    const int col = idx >> 9;               // K/8 = 512 chunks per row
    const int d   = idx & 511;
    const float s = scf[col * GROUPS + (d >> 4)];
    const int4 p  = ((const int4*)packed)[idx];
    const int vals[4] = {p.x, p.y, p.z, p.w};
    union { _Float16 h[8]; s16x8 v; } r;
    #pragma unroll
    for (int e = 0; e < 4; ++e) {
      int b = vals[e] & 255;
      r.h[2 * e]     = (_Float16)((float)((b & 15) - 8) * s);
      r.h[2 * e + 1] = (_Float16)((float)(((b >> 4) & 15) - 8) * s);
    }
    *(s16x8*)(wf + (size_t)idx * 8) = r.v;
  }
}

// ---------------------------------------------------------------------------
// BIG-PATH GEMM (R16): 256x256 block, 8 waves (2m x 4n), BK=64.
// R15 post-mortem: sched_barrier(0) fences pinned "all loads then all MFMAs"
// per sub-phase -> matrix pipe idle in every load window (m141 lesson).
// R16: NO intra-tile fences — loads sit in sub-phase source order and the
// compiler emits its native counted-lgkmcnt software pipeline (m97-verified).
// t-loop unrolled 2x so `cur` is static -> LDS addresses loop-invariant.
// Sync structure unchanged from verified R15: one entry vmcnt(0)+barrier per
// tile (stages of tile t are the only outstanding vmem at entry; stages for
// t+1 write buf cur^1 only; each wave's ds_reads are consumed by in-tile
// MFMAs so drained before the next entry barrier).
// ---------------------------------------------------------------------------
__global__ __launch_bounds__(512, 2) void q4gemm_big_kernel(
    const u16* __restrict__ xh,      // fp16 natural [M][K]
    const u16* __restrict__ wf,      // fp16 W [N][K]
    float* __restrict__ out,
    const int* __restrict__ modep)
{
  if (modep && modep[0] != 0) return;

  __shared__ _Float16 AsA[2][256 * 64];   // 64 KiB
  __shared__ _Float16 AsB[2][256 * 64];   // 64 KiB

  const int tid  = threadIdx.x;
  const int lane = tid & 63;
  const int wv   = tid >> 6;             // 0..7
  const int wm   = (wv >> 2) * 128;      // 2 waves in m
  const int wn   = (wv & 3) * 64;        // 4 waves in n
  const int ln15 = lane & 15;
  const int lk   = lane >> 4;            // 0..3

  // XCD swizzle: 1376 = 8 * 172; per-XCD contiguous f, bm-fastest within a
  // bn group -> same-XCD neighbors share the 2MB B panel.
  int bid = blockIdx.x;
  int f   = (bid & 7) * 172 + (bid >> 3);
  int bn  = f / 32;                      // 0..42
  int bm  = f - bn * 32;                 // 0..31
  const int m0 = bm * 256;
  const int n0 = bn * 256;

  // Staging addresses: LDS[row][slot] = G[row][slot ^ (row&7)] (16B chunks).
  const int srow  = lane >> 3;           // 0..7
  const int sperm = (lane & 7) ^ srow;
  const u16* abase[4];
  const u16* bbase[4];
  #pragma unroll
  for (int q = 0; q < 4; ++q) {
    int row = q * 64 + wv * 8 + srow;
    abase[q] = xh + (size_t)(m0 + row) * K_DIM + sperm * 8;
    bbase[q] = wf + (size_t)(n0 + row) * K_DIM + sperm * 8;
  }

#define STAGE_ALL(PB, T) do { \
    _Float16* da = &AsA[(PB)][0]; \
    _Float16* db = &AsB[(PB)][0]; \
    _Pragma("unroll") \
    for (int q = 0; q < 4; ++q) \
      __builtin_amdgcn_global_load_lds( \
          (const __attribute__((address_space(1))) void*)(abase[q] + (T) * 64), \
          (__attribute__((address_space(3))) void*)(da + q * 4096 + wv * 512), \
          16, 0, 0); \
    _Pragma("unroll") \
    for (int q = 0; q < 4; ++q) \
      __builtin_amdgcn_global_load_lds( \
          (const __attribute__((address_space(1))) void*)(bbase[q] + (T) * 64), \
          (__attribute__((address_space(3))) void*)(db + q * 4096 + wv * 512), \
          16, 0, 0); \
  } while (0)

  // One tile's compute on buffer CUR — loads in sub-phase source order, NO
  // fences: the compiler interleaves ds_read issue among MFMAs with counted
  // lgkmcnt (its native software pipeline).
#define TILE_BODY(CUR) do { \
    const _Float16* Ab = &AsA[(CUR)][0]; \
    const _Float16* Bb = &AsB[(CUR)][0]; \
    const int slotx = ln15 & 7; \
    const int slot0 = lk ^ slotx; \
    const int slot1 = (4 + lk) ^ slotx; \
    f16x8 bf0[4], bf1[4], afA[4], afB[4]; \
    _Pragma("unroll") \
    for (int j = 0; j < 4; ++j) \
      bf0[j] = *(const f16x8*)&Bb[(wn + j * 16 + ln15) * 64 + slot0 * 8]; \
    _Pragma("unroll") \
    for (int ii = 0; ii < 4; ++ii) \
      afA[ii] = *(const f16x8*)&Ab[(wm + ii * 16 + ln15) * 64 + slot0 * 8]; \
    __builtin_amdgcn_s_setprio(1); \
    _Pragma("unroll") \
    for (int ii = 0; ii < 4; ++ii) { \
      acc[ii][0] = __builtin_amdgcn_mfma_f32_16x16x32_f16(afA[ii], bf0[0], acc[ii][0], 0, 0, 0); \
      acc[ii][1] = __builtin_amdgcn_mfma_f32_16x16x32_f16(afA[ii], bf0[1], acc[ii][1], 0, 0, 0); \
      acc[ii][2] = __builtin_amdgcn_mfma_f32_16x16x32_f16(afA[ii], bf0[2], acc[ii][2], 0, 0, 0); \
      acc[ii][3] = __builtin_amdgcn_mfma_f32_16x16x32_f16(afA[ii], bf0[3], acc[ii][3], 0, 0, 0); \
    } \
    _Pragma("unroll") \
    for (int ii = 0; ii < 4; ++ii) \
      afB[ii] = *(const f16x8*)&Ab[(wm + (4 + ii) * 16 + ln15) * 64 + slot0 * 8]; \
    _Pragma("unroll") \
    for (int ii = 0; ii < 4; ++ii) { \
      acc[4 + ii][0] = __builtin_amdgcn_mfma_f32_16x16x32_f16(afB[ii], bf0[0], acc[4 + ii][0], 0, 0, 0); \
      acc[4 + ii][1] = __builtin_amdgcn_mfma_f32_16x16x32_f16(afB[ii], bf0[1], acc[4 + ii][1], 0, 0, 0); \
      acc[4 + ii][2] = __builtin_amdgcn_mfma_f32_16x16x32_f16(afB[ii], bf0[2], acc[4 + ii][2], 0, 0, 0); \
      acc[4 + ii][3] = __builtin_amdgcn_mfma_f32_16x16x32_f16(afB[ii], bf0[3], acc[4 + ii][3], 0, 0, 0); \
    } \
    _Pragma("unroll") \
    for (int j = 0; j < 4; ++j) \
      bf1[j] = *(const f16x8*)&Bb[(wn + j * 16 + ln15) * 64 + slot1 * 8]; \
    _Pragma("unroll") \
    for (int ii = 0; ii < 4; ++ii) \
      afA[ii] = *(const f16x8*)&Ab[(wm + ii * 16 + ln15) * 64 + slot1 * 8]; \
    _Pragma("unroll") \
    for (int ii = 0; ii < 4; ++ii) { \
      acc[ii][0] = __builtin_amdgcn_mfma_f32_16x16x32_f16(afA[ii], bf1[0], acc[ii][0], 0, 0, 0); \
      acc[ii][1] = __builtin_amdgcn_mfma_f32_16x16x32_f16(afA[ii], bf1[1], acc[ii][1], 0, 0, 0); \
      acc[ii][2] = __builtin_amdgcn_mfma_f32_16x16x32_f16(afA[ii], bf1[2], acc[ii][2], 0, 0, 0); \
      acc[ii][3] = __builtin_amdgcn_mfma_f32_16x16x32_f16(afA[ii], bf1[3], acc[ii][3], 0, 0, 0); \
    } \
    _Pragma("unroll") \
    for (int ii = 0; ii < 4; ++ii) \
      afB[ii] = *(const f16x8*)&Ab[(wm + (4 + ii) * 16 + ln15) * 64 + slot1 * 8]; \
    _Pragma("unroll") \
    for (int ii = 0; ii < 4; ++ii) { \
      acc[4 + ii][0] = __builtin_amdgcn_mfma_f32_16x16x32_f16(afB[ii], bf1[0], acc[4 + ii][0], 0, 0, 0); \
      acc[4 + ii][1] = __builtin_amdgcn_mfma_f32_16x16x32_f16(afB[ii], bf1[1], acc[4 + ii][1], 0, 0, 0); \
      acc[4 + ii][2] = __builtin_amdgcn_mfma_f32_16x16x32_f16(afB[ii], bf1[2], acc[4 + ii][2], 0, 0, 0); \
      acc[4 + ii][3] = __builtin_amdgcn_mfma_f32_16x16x32_f16(afB[ii], bf1[3], acc[4 + ii][3], 0, 0, 0); \
    } \
    __builtin_amdgcn_s_setprio(0); \
  } while (0)

  f32x4 acc[8][4];
  #pragma unroll
  for (int i = 0; i < 8; ++i)
    #pragma unroll
    for (int j = 0; j < 4; ++j)
      acc[i][j] = f32x4{0.f, 0.f, 0.f, 0.f};

  // prologue: stage tile 0 into buf 0
  STAGE_ALL(0, 0);

  #pragma unroll 1
  for (int tp = 0; tp < 32; ++tp) {
    const int t0 = 2 * tp;

    // ---- tile t0 on buf 0 ----
    asm volatile("s_waitcnt vmcnt(0)" ::: "memory");
    __builtin_amdgcn_s_barrier();
    STAGE_ALL(1, t0 + 1);                // t0+1 <= 63 always
    TILE_BODY(0);

    // ---- tile t0+1 on buf 1 ----
    asm volatile("s_waitcnt vmcnt(0)" ::: "memory");
    __builtin_amdgcn_s_barrier();
    if (t0 + 2 < 64) STAGE_ALL(0, t0 + 2);
    TILE_BODY(1);
  }

  // epilogue: C/D col=lane&15, row=(lane>>4)*4+reg — nontemporal stores.
  #pragma unroll
  for (int i = 0; i < 8; ++i) {
    int r0 = m0 + wm + i * 16 + (lane >> 4) * 4;
    #pragma unroll
    for (int j = 0; j < 4; ++j) {
      int cc = n0 + wn + j * 16 + ln15;
      #pragma unroll
      for (int r = 0; r < 4; ++r)
        __builtin_nontemporal_store(acc[i][j][r], &out[(size_t)(r0 + r) * N_DIM + cc]);
    }
  }
#undef STAGE_ALL
#undef TILE_BODY
}

// ---------------------------------------------------------------------------
// MID PATH (R10 verified; runs only if ws fits 90MB but not 157MB).
// ---------------------------------------------------------------------------
__global__ __launch_bounds__(256) void convert_x_perm_kernel(
    const float* __restrict__ xf, u16* __restrict__ xh,
    const int* __restrict__ modep) {
  if (modep && modep[0] != 0) return;
  const int total8 = M_DIM * (K_DIM / 8);
  int idx = blockIdx.x * 256 + threadIdx.x;
  const int stride = gridDim.x * 256;
  for (; idx < total8; idx += stride) {
    const float4* p = (const float4*)(xf + (size_t)idx * 8);
    float4 a = p[0], b = p[1];
    union { _Float16 h[8]; s16x8 v; } r;
    r.h[0] = (_Float16)a.x; r.h[1] = (_Float16)b.x;
    r.h[2] = (_Float16)a.y; r.h[3] = (_Float16)b.y;
    r.h[4] = (_Float16)a.z; r.h[5] = (_Float16)b.z;
    r.h[6] = (_Float16)a.w; r.h[7] = (_Float16)b.w;
    *(s16x8*)(xh + (size_t)idx * 8) = r.v;
  }
}

__global__ __launch_bounds__(256) void repack_w_kernel(
    const int* __restrict__ packed, u32* __restrict__ wq) {
  const int total = N_DIM * WQROW;
  int idx = blockIdx.x * 256 + threadIdx.x;
  const int stride = gridDim.x * 256;
  for (; idx < total; idx += stride) {
    const int4 p = ((const int4*)packed)[idx];
    wq[idx] = (u32)(p.x & 255) | ((u32)(p.y & 255) << 8) |
              ((u32)(p.z & 255) << 16) | ((u32)p.w << 24);
  }
}

__device__ __forceinline__ f16x8 dq8(u32 q, h2 s2) {
  const u32 M = 0x000F000Fu, G = 0x64006400u;
  const h2 bias = {(_Float16)(-1032.0f), (_Float16)(-1032.0f)};
  union { u32 u; h2 h; } a0, a1, a2, a3;
  a0.u = (q & M) | G;
  a1.u = ((q >> 4) & M) | G;
  a2.u = ((q >> 8) & M) | G;
  a3.u = ((q >> 12) & M) | G;
  a0.h = (a0.h + bias) * s2;
  a1.h = (a1.h + bias) * s2;
  a2.h = (a2.h + bias) * s2;
  a3.h = (a3.h + bias) * s2;
  union { u32 u[4]; f16x8 f; } r;
  r.u[0] = a0.u; r.u[1] = a1.u; r.u[2] = a2.u; r.u[3] = a3.u;
  return r.f;
}

__global__ __launch_bounds__(256, 2) void q4gemm_mid_kernel(
    const u16* __restrict__ xh, const u32* __restrict__ wq,
    const float* __restrict__ scf, float* __restrict__ out,
    const int* __restrict__ modep)
{
  if (modep && modep[0] != 0) return;

  __shared__ _Float16 As[3][128 * 64];

  const int tid  = threadIdx.x;
  const int lane = tid & 63;
  const int wv   = tid >> 6;
  const int wn   = wv * 64;
  const int ln15 = lane & 15;
  const int lk   = lane >> 4;

  int bid = blockIdx.x;
  int f   = (bid & 7) * 344 + (bid >> 3);
  int bn  = f / 64;
  int bm  = f - bn * 64;
  const int m0 = bm * 128;
  const int n0 = bn * 256;

  const u16* abase[4];
  #pragma unroll
  for (int q = 0; q < 4; ++q) {
    int row = q * 32 + wv * 8 + (lane >> 3);
    abase[q] = xh + (size_t)(m0 + row) * K_DIM + (((lane & 7) ^ (lane >> 3)) * 8);
  }

#define STAGE(PB, T) do { \
    _Float16* dst = &As[(PB)][0]; \
    _Pragma("unroll") \
    for (int q = 0; q < 4; ++q) \
      __builtin_amdgcn_global_load_lds( \
          (const __attribute__((address_space(1))) void*)(abase[q] + (T) * 64), \
          (__attribute__((address_space(3))) void*)(dst + q * 2048 + wv * 512), \
          16, 0, 0); \
  } while (0)

#define LOADB(RB, T) do { \
    _Pragma("unroll") \
    for (int j = 0; j < 4; ++j) { \
      RB[j]     = wq[pcol[j] + (T) * 8]; \
      RB[j + 4] = wq[pcol[j] + (T) * 8 + 4]; \
    } \
  } while (0)

#define COMPUTE(RB, PB) do { \
    const _Float16* asb = &As[(PB)][0]; \
    _Pragma("unroll") \
    for (int kkc = 0; kkc < 2; ++kkc) { \
      f16x8 bfr0 = dq8(RB[kkc * 4 + 0], s2[0]); \
      f16x8 bfr1 = dq8(RB[kkc * 4 + 1], s2[1]); \
      f16x8 bfr2 = dq8(RB[kkc * 4 + 2], s2[2]); \
      f16x8 bfr3 = dq8(RB[kkc * 4 + 3], s2[3]); \
      _Pragma("unroll") \
      for (int i = 0; i < 8; ++i) { \
        const int row  = i * 16 + ln15; \
        const int slot = (kkc * 4 + lk) ^ (ln15 & 7); \
        f16x8 af = *(const f16x8*)&asb[row * 64 + slot * 8]; \
        acc[i][0] = __builtin_amdgcn_mfma_f32_16x16x32_f16(af, bfr0, acc[i][0], 0, 0, 0); \
        acc[i][1] = __builtin_amdgcn_mfma_f32_16x16x32_f16(af, bfr1, acc[i][1], 0, 0, 0); \
        acc[i][2] = __builtin_amdgcn_mfma_f32_16x16x32_f16(af, bfr2, acc[i][2], 0, 0, 0); \
        acc[i][3] = __builtin_amdgcn_mfma_f32_16x16x32_f16(af, bfr3, acc[i][3], 0, 0, 0); \
      } \
    } \
  } while (0)

  int pcol[4], scol[4];
  #pragma unroll
  for (int j = 0; j < 4; ++j) {
    int col = n0 + wn + j * 16 + ln15;
    pcol[j] = col * WQROW + lk;
    scol[j] = col * GROUPS;
  }

  f32x4 acc[8][4];
  #pragma unroll
  for (int i = 0; i < 8; ++i)
    #pragma unroll
    for (int j = 0; j < 4; ++j)
      acc[i][j] = f32x4{0.f, 0.f, 0.f, 0.f};

  u32 rbE[8], rbO[8];
  float snextf[4];
  h2 s2[4];

  STAGE(0, 0);
  STAGE(1, 1);
  LOADB(rbE, 0);
  LOADB(rbO, 1);
  #pragma unroll
  for (int j = 0; j < 4; ++j) snextf[j] = scf[scol[j]];
  asm volatile("s_waitcnt vmcnt(0)" ::: "memory");

  int p0 = 0, p1 = 1, p2 = 2;

  for (int tp = 0; tp < 32; ++tp) {
    const int t0 = 2 * tp;
    const int t1 = t0 + 1;

    asm volatile("s_waitcnt vmcnt(12)" ::: "memory");
    __builtin_amdgcn_s_barrier();
    __builtin_amdgcn_sched_barrier(0);

    #pragma unroll
    for (int j = 0; j < 4; ++j) {
      _Float16 sh = (_Float16)snextf[j];
      s2[j] = h2{sh, sh};
    }
    if (t0 + 2 < 64) STAGE(p2, t0 + 2);

    __builtin_amdgcn_s_setprio(1);
    COMPUTE(rbE, p0);
    __builtin_amdgcn_s_setprio(0);

    if (t0 + 2 < 64) LOADB(rbE, t0 + 2);
    {
      const int gn = (tp + 1 > 31) ? 31 : (tp + 1);
      #pragma unroll
      for (int j = 0; j < 4; ++j) snextf[j] = scf[scol[j] + gn];
    }

    if (tp == 31) {
      asm volatile("s_waitcnt vmcnt(0)" ::: "memory");
    } else {
      asm volatile("s_waitcnt vmcnt(12)" ::: "memory");
    }
    __builtin_amdgcn_s_barrier();
    __builtin_amdgcn_sched_barrier(0);

    if (t1 + 2 < 64) STAGE(p0, t1 + 2);

    __builtin_amdgcn_s_setprio(1);
    COMPUTE(rbO, p1);
    __builtin_amdgcn_s_setprio(0);

    if (t1 + 2 < 64) LOADB(rbO, t1 + 2);

    int tmp = p2; p2 = p1; p1 = p0; p0 = tmp;
  }

  #pragma unroll
  for (int i = 0; i < 8; ++i) {
    int r0 = m0 + i * 16 + (lane >> 4) * 4;
    #pragma unroll
    for (int j = 0; j < 4; ++j) {
      int cc = n0 + wn + j * 16 + ln15;
      #pragma unroll
      for (int r = 0; r < 4; ++r)
        out[(size_t)(r0 + r) * N_DIM + cc] = acc[i][j][r];
    }
  }
#undef STAGE
#undef LOADB
#undef COMPUTE
}

// ---------------------------------------------------------------------------
// SLOW FALLBACK (any mode; skips mode 0 when a fast path ran).
// ---------------------------------------------------------------------------
__global__ __launch_bounds__(256) void q4gemm_slow_kernel(
    const void* __restrict__ xraw,
    const int*  __restrict__ packed,
    const void* __restrict__ scraw,
    float* __restrict__ out,
    const int* __restrict__ modep,
    int skip0)
{
  const int mode = modep ? modep[0] : 0;
  if (skip0 && mode == 0) return;

  __shared__ u16 Asl[128 * LDSK];
  __shared__ u16 Bsl[128 * LDSK];

  const int tid  = threadIdx.x;
  const int lane = tid & 63;
  const int wv   = tid >> 6;
  const int wm   = (wv >> 1) * 64;
  const int wn   = (wv & 1) * 64;
  const int n0   = blockIdx.x * 128;
  const int m0   = blockIdx.y * 128;

  f32x4 acc[4][4];
  #pragma unroll
  for (int i = 0; i < 4; ++i)
    #pragma unroll
    for (int j = 0; j < 4; ++j)
      acc[i][j] = f32x4{0.f, 0.f, 0.f, 0.f};

  const int lrow16 = lane & 15;
  const int lk8    = (lane >> 4) * 8;

  for (int k0 = 0; k0 < K_DIM; k0 += 64) {
    if (mode == 0) {
      const float* xf = (const float*)xraw;
      #pragma unroll
      for (int it = 0; it < 4; ++it) {
        int s = tid + it * 256;
        int row = s >> 3, c8 = (s & 7) * 8;
        const float4* p = (const float4*)(xf + (size_t)(m0 + row) * K_DIM + k0 + c8);
        float4 v0 = p[0], v1 = p[1];
        u16 tmp[8] = { f2bf(v0.x), f2bf(v0.y), f2bf(v0.z), f2bf(v0.w),
                       f2bf(v1.x), f2bf(v1.y), f2bf(v1.z), f2bf(v1.w) };
        *(s16x8*)&Asl[row * LDSK + c8] = *(const s16x8*)tmp;
      }
    } else if (mode == 1) {
      const u16* xhh = (const u16*)xraw;
      #pragma unroll
      for (int it = 0; it < 4; ++it) {
        int s = tid + it * 256;
        int row = s >> 3, c8 = (s & 7) * 8;
        s16x8 v = *(const s16x8*)(xhh + (size_t)(m0 + row) * K_DIM + k0 + c8);
        u16 tmp[8];
        #pragma unroll
        for (int j = 0; j < 8; ++j) tmp[j] = f2bf(h2f((u16)v[j]));
        *(s16x8*)&Asl[row * LDSK + c8] = *(const s16x8*)tmp;
      }
    } else {
      const u16* xhh = (const u16*)xraw;
      #pragma unroll
      for (int it = 0; it < 4; ++it) {
        int s = tid + it * 256;
        int row = s >> 3, c8 = (s & 7) * 8;
        s16x8 v = *(const s16x8*)(xhh + (size_t)(m0 + row) * K_DIM + k0 + c8);
        *(s16x8*)&Asl[row * LDSK + c8] = v;
      }
    }

    {
      int row  = tid >> 1;
      int half = tid & 1;
      int srw  = n0 + row;
      int g    = k0 >> 7;
      float scale;
      if      (mode == 0) scale = ((const float*)scraw)[(size_t)srw * GROUPS + g];
      else if (mode == 1) scale = h2f(((const u16*)scraw)[(size_t)srw * GROUPS + g]);
      else                scale = bf2f(((const u16*)scraw)[(size_t)srw * GROUPS + g]);

      const int4* pp = (const int4*)(packed + (size_t)srw * (K_DIM / 2) + (k0 >> 1) + half * 16);
      #pragma unroll
      for (int j = 0; j < 4; ++j) {
        int4 pv = pp[j];
        int vals[4] = {pv.x, pv.y, pv.z, pv.w};
        u16 w[8];
        #pragma unroll
        for (int e = 0; e < 4; ++e) {
          int b = vals[e] & 255;
          w[e * 2]     = f2bf(scale * (float)((b & 15) - 8));
          w[e * 2 + 1] = f2bf(scale * (float)(((b >> 4) & 15) - 8));
        }
        int i0 = half * 16 + j * 4;
        *(s16x8*)&Bsl[row * LDSK + i0 * 2] = *(const s16x8*)w;
      }
    }
    __syncthreads();

    #pragma unroll
    for (int kk = 0; kk < 64; kk += 32) {
      s16x8 af[4], bfr[4];
      int klane = kk + lk8;
      #pragma unroll
      for (int i = 0; i < 4; ++i)
        af[i] = *(const s16x8*)&Asl[(wm + i * 16 + lrow16) * LDSK + klane];
      #pragma unroll
      for (int i = 0; i < 4; ++i)
        bfr[i] = *(const s16x8*)&Bsl[(wn + i * 16 + lrow16) * LDSK + klane];
      #pragma unroll
      for (int i = 0; i < 4; ++i)
        #pragma unroll
        for (int j = 0; j < 4; ++j)
          acc[i][j] = __builtin_amdgcn_mfma_f32_16x16x32_bf16(af[i], bfr[j], acc[i][j], 0, 0, 0);
    }
    __syncthreads();
  }

  #pragma unroll
  for (int i = 0; i < 4; ++i) {
    int rbase = m0 + wm + i * 16 + ((lane >> 4) * 4);
    #pragma unroll
    for (int j = 0; j < 4; ++j) {
      int c = n0 + wn + j * 16 + (lane & 15);
      #pragma unroll
      for (int r = 0; r < 4; ++r)
        out[(size_t)(rbase + r) * N_DIM + c] = acc[i][j][r];
    }
  }
}

extern "C" void kernel_launch(void* const* d_in, const int* in_sizes, int n_in,
                              void* d_out, int out_size, void* d_ws, size_t ws_size,
                              hipStream_t stream) {
  const void* x      = d_in[0];
  const int*  packed = (const int*)d_in[1];
  const void* scales = d_in[2];
  float* out = (float*)d_out;

  const size_t XB = (size_t)M_DIM * K_DIM * 2;        // 67,108,864 B
  const size_t WF = (size_t)N_DIM * K_DIM * 2;        // 90,177,536 B
  const size_t WQ = (size_t)N_DIM * WQROW * 4;        // 22,544,384 B
  const size_t NEED_BIG = 256 + XB + WF;              // ~157.3 MB
  const size_t NEED_MID = 256 + XB + WQ;              // ~89.7 MB

  int* mode_flag = nullptr;
  if (ws_size >= 4) {
    mode_flag = (int*)d_ws;
    probe_mode_kernel<<<dim3(1), dim3(256), 0, stream>>>(scales, mode_flag);
  }

  int fast = 0;
  if (mode_flag && ws_size >= NEED_BIG) fast = 2;
  else if (mode_flag && ws_size >= NEED_MID) fast = 1;

  if (fast == 2) {
    u16* xh = (u16*)((char*)d_ws + 256);
    u16* wf = (u16*)((char*)d_ws + 256 + XB);
    convert_x_nat_kernel<<<dim3(2048), dim3(256), 0, stream>>>(
        (const float*)x, xh, mode_flag);
    dequant_w_kernel<<<dim3(2048), dim3(256), 0, stream>>>(
        packed, (const float*)scales, wf, mode_flag);
    q4gemm_big_kernel<<<dim3(1376), dim3(512), 0, stream>>>(
        xh, wf, out, mode_flag);
  } else if (fast == 1) {
    u16* xh = (u16*)((char*)d_ws + 256);
    u32* wq = (u32*)((char*)d_ws + 256 + XB);
    convert_x_perm_kernel<<<dim3(2048), dim3(256), 0, stream>>>(
        (const float*)x, xh, mode_flag);
    repack_w_kernel<<<dim3(2048), dim3(256), 0, stream>>>(packed, wq);
    q4gemm_mid_kernel<<<dim3(2752), dim3(256), 0, stream>>>(
        xh, wq, (const float*)scales, out, mode_flag);
  }

  q4gemm_slow_kernel<<<dim3(N_DIM / 128, M_DIM / 128), dim3(256), 0, stream>>>(
      x, packed, scales, out, mode_flag, fast);
}